// Round 8
// baseline (592.014 us; speedup 1.0000x reference)
//
#include <hip/hip_runtime.h>

// Problem constants (VectorQuantizer: B=16, D=64, H=64, W=64, K=1024)
#define DD 64
#define KK 1024
#define NPTS 65536      // B*H*W
#define TOTAL 4194304   // B*D*H*W

// Output layout (concatenated flat, all read as float32 by harness)
#define OFF_L1 4194304
#define OFF_L2 4194305
#define OFF_IDX 4194306

#define WS_ENORM 64      // ws float offset of enorm[1024]

#define PT 128           // points per block
#define NBLK (NPTS / PT) // 512

// ---------------- kernel 1: codebook squared norms (wide, ILP-deep) ----------------
__global__ __launch_bounds__(256) void enorm_kernel(const float* __restrict__ e,
                                                    float* __restrict__ enorm) {
    __shared__ float red[64 * 4];
    const int tid = threadIdx.x;
    const int c = tid & 63;
    const int q = tid >> 6;
    const int k = blockIdx.x * 64 + c;
    float s = 0.f;
#pragma unroll
    for (int r = 0; r < 16; ++r) {
        const float v = e[(q * 16 + r) * KK + k];
        s = fmaf(v, v, s);
    }
    red[c * 4 + q] = s;
    __syncthreads();
    if (tid < 64) {
        enorm[blockIdx.x * 64 + tid] =
            red[tid * 4] + red[tid * 4 + 1] + red[tid * 4 + 2] + red[tid * 4 + 3];
    }
}

// ---------------- kernel 2: scalar-operand argmin + quantize + loss ----------------
// 256 threads = 4 waves; 128 points/block; lane = point, K split in halves
// (wave&1). e-row addresses are wave-uniform -> SMEM (s_load) path; x via one
// conflict-free ds_read_b32 per d. Per-lane argmin (no cross-lane reduce);
// 2-way half-merge in LDS; fused quantize/loss/ticket epilogue.
__global__ __launch_bounds__(256) void vq_scalar(const float* __restrict__ x,
                                                 const float* __restrict__ e,
                                                 const float* __restrict__ enorm,
                                                 float* __restrict__ out,
                                                 float* __restrict__ sum,
                                                 unsigned* __restrict__ cnt) {
    __shared__ __align__(16) float xs[DD * PT];   // 32 KB [d][p]; live to epilogue
    __shared__ float mv[PT * 2];                  // half-merge values
    __shared__ float mif[PT * 2];                 // half-merge indices (as float)
    __shared__ int ks[PT];
    __shared__ float red[4];

    const int tid = threadIdx.x;
    const int n0 = blockIdx.x * PT;
    const int b = n0 >> 12;
    const int hw0 = n0 & 4095;

    // ---- stage x tile: xs[d][p], 512B contiguous per 32 lanes ----
    {
        const int c4 = (tid & 31) * 4;
        const int r = tid >> 5;           // 0..7
#pragma unroll
        for (int dr = 0; dr < 8; ++dr) {
            const int d = dr * 8 + r;
            *(float4*)(&xs[d * PT + c4]) =
                *(const float4*)(x + ((b * DD + d) << 12) + hw0 + c4);
        }
    }
    __syncthreads();

    const int w = tid >> 6;               // wave 0..3
    const int lane = tid & 63;
    const int p = (w >> 1) * 64 + lane;   // this lane's point
    const int kh = w & 1;                 // k-half 0/1
    const int kbase = kh * 512;

    float bv = 3.4e38f;
    int bi = 0;

    for (int g = 0; g < 8; ++g) {         // 8 groups of 64 codes per half
        const int kc = kbase + g * 64;

        float acc[64];
#pragma unroll
        for (int c = 0; c < 64; ++c) acc[c] = 0.f;

#pragma unroll 2
        for (int d = 0; d < DD; ++d) {
            const float xv = xs[d * PT + p];          // ds_read_b32, 2-way free
            const float* erow = e + d * KK + kc;      // uniform -> s_load_dwordx16
#pragma unroll
            for (int c = 0; c < 64; ++c)
                acc[c] = fmaf(xv, erow[c], acc[c]);   // v_fma with SGPR src
        }

        const float* enr = enorm + kc;                // uniform -> s_load
#pragma unroll
        for (int c = 0; c < 64; ++c) {
            const float dist = fmaf(-2.f, acc[c], enr[c]);
            // strict <: k scanned in ascending order per lane -> smallest wins ties
            if (dist < bv) { bv = dist; bi = kc + c; }
        }
    }

    // ---- 2-way half merge via LDS ----
    mv[p * 2 + kh] = bv;
    mif[p * 2 + kh] = (float)bi;
    __syncthreads();
    if (tid < PT) {
        const float v0 = mv[tid * 2], v1 = mv[tid * 2 + 1];
        const float i0 = mif[tid * 2], i1 = mif[tid * 2 + 1];
        const float bidx = (v1 < v0) ? i1 : i0;   // tie -> half0 (smaller index)
        ks[tid] = (int)bidx;
        out[OFF_IDX + n0 + tid] = bidx;
    }
    __syncthreads();

    // ---- fused quantize + loss: thread = (point, d-half); xs still valid ----
    const int pp = tid & 127;
    const int dh = tid >> 7;
    const int kp = ks[pp];
    const float* ecol = e + kp;           // e[d*KK + kp], L2-hot scatter
    float lacc = 0.f;
#pragma unroll 8
    for (int dd = 0; dd < 32; ++dd) {
        const int d = dh * 32 + dd;
        const float q = ecol[d * KK];
        const float xv = xs[d * PT + pp];
        out[((b * DD + d) << 12) + hw0 + pp] = q;   // coalesced across lanes
        const float df = xv - q;
        lacc = fmaf(df, df, lacc);
    }

#pragma unroll
    for (int off = 32; off > 0; off >>= 1) lacc += __shfl_down(lacc, off, 64);
    if ((tid & 63) == 0) red[tid >> 6] = lacc;
    __syncthreads();
    if (tid == 0) {
        atomicAdd(sum, red[0] + red[1] + red[2] + red[3]);
        __threadfence();
        const unsigned old = atomicAdd(cnt, 1u);
        if (old == (NBLK - 1)) {          // last block: all sums visible
            const float s = atomicAdd(sum, 0.0f);
            const float m = s * (1.0f / (float)TOTAL);
            out[OFF_L1] = m;   // dictionary_loss
            out[OFF_L2] = m;   // commitment_loss (numerically identical)
        }
    }
}

extern "C" void kernel_launch(void* const* d_in, const int* in_sizes, int n_in,
                              void* d_out, int out_size, void* d_ws, size_t ws_size,
                              hipStream_t stream) {
    const float* x = (const float*)d_in[0];      // [16,64,64,64]
    const float* e = (const float*)d_in[1];      // [64,1024]
    float* out = (float*)d_out;

    float* wsf = (float*)d_ws;
    float* sum = wsf;                            // [0]
    unsigned* cnt = (unsigned*)d_ws + 1;         // [1]
    float* enorm = wsf + WS_ENORM;

    hipMemsetAsync(d_ws, 0, 8, stream);          // sum + ticket
    enorm_kernel<<<16, 256, 0, stream>>>(e, enorm);
    vq_scalar<<<NBLK, 256, 0, stream>>>(x, e, enorm, out, sum, cnt);
}

// Round 9
// 191.163 us; speedup vs baseline: 3.0969x; 3.0969x over previous
//
#include <hip/hip_runtime.h>

// VectorQuantizer: B=16, D=64, H=64, W=64, K=1024
#define DD 64
#define KK 1024
#define NPTS 65536
#define TOTAL 4194304

// Output layout (flat f32): quantized[4194304], L1, L2, idx[65536]
#define OFF_L1 4194304
#define OFF_L2 4194305
#define OFF_IDX 4194306

// ws layout: [0] f32 sum, [1] i32 rescue_cnt, enorm @ float 64,
// rescue list @ int 1088 (cap 8192), ehT @ byte 65536, elT after.
#define WS_ENORM_F 64
#define WS_LIST_I 1088
#define RESCUE_CAP 8192
#define WS_EHT_BYTE 65536
#define WS_ELT_BYTE (65536 + 1024 * 72 * 2)

#define EPAD 72      // padded d-stride (ushorts) for bf16 rows [k][d]
#define XPAD 68      // padded stride (floats) for fp32 LDS tiles
#define MARGIN 0.05f // conservative bound on bf16x3 distance error (x2)

typedef __attribute__((ext_vector_type(8))) short short8;
typedef __attribute__((ext_vector_type(4))) float f32x4;

__device__ __forceinline__ unsigned short bf16_rne(float f) {
    unsigned b = __float_as_uint(f);
    return (unsigned short)((b + 0x7FFFu + ((b >> 16) & 1u)) >> 16);
}
__device__ __forceinline__ float bf16_to_f(unsigned short h) {
    return __uint_as_float(((unsigned)h) << 16);
}

// ---------- kernel 1: enorm + split-transpose codebook to [k][d] bf16 hi/lo ----------
__global__ __launch_bounds__(256) void prep_kernel(const float* __restrict__ e,
                                                   float* __restrict__ enorm,
                                                   unsigned short* __restrict__ ehT,
                                                   unsigned short* __restrict__ elT) {
    __shared__ __align__(16) float et[DD * XPAD];
    __shared__ float enred[64 * 4];
    const int tid = threadIdx.x;
    const int k0 = blockIdx.x * 64;
    {   // load e[d][k0..k0+63] coalesced
        const int d = tid >> 2, kq = tid & 3;
#pragma unroll
        for (int j = 0; j < 4; ++j) {
            const int kk = kq * 16 + j * 4;
            *(float4*)(&et[d * XPAD + kk]) = *(const float4*)(e + d * KK + k0 + kk);
        }
    }
    __syncthreads();
    const int k = tid >> 2, dq = tid & 3;
    unsigned hu[8], lu[8];
    float s2 = 0.f;
#pragma unroll
    for (int s = 0; s < 16; s += 2) {
        const int d0 = dq * 16 + s;
        const float f0 = et[d0 * XPAD + k];
        const float f1 = et[(d0 + 1) * XPAD + k];
        s2 = fmaf(f0, f0, s2);
        s2 = fmaf(f1, f1, s2);
        const unsigned short h0 = bf16_rne(f0), h1 = bf16_rne(f1);
        const unsigned short l0 = bf16_rne(f0 - bf16_to_f(h0));
        const unsigned short l1 = bf16_rne(f1 - bf16_to_f(h1));
        hu[s >> 1] = (unsigned)h0 | ((unsigned)h1 << 16);
        lu[s >> 1] = (unsigned)l0 | ((unsigned)l1 << 16);
    }
    const int row = (k0 + k) * EPAD + dq * 16;
    *(uint4*)(ehT + row) = make_uint4(hu[0], hu[1], hu[2], hu[3]);
    *(uint4*)(ehT + row + 8) = make_uint4(hu[4], hu[5], hu[6], hu[7]);
    *(uint4*)(elT + row) = make_uint4(lu[0], lu[1], lu[2], lu[3]);
    *(uint4*)(elT + row + 8) = make_uint4(lu[4], lu[5], lu[6], lu[7]);
    enred[k * 4 + dq] = s2;
    __syncthreads();
    if (tid < 64)
        enorm[k0 + tid] = enred[tid * 4] + enred[tid * 4 + 1] + enred[tid * 4 + 2] + enred[tid * 4 + 3];
}

// ---------- kernel 2: MFMA bf16x3 distances + argmin(+2nd best) + quantize + loss ----------
// 256 thr = 4 waves; block = 64 pts x all 1024 codes (8 codetiles of 128).
// Wave tile 32 pts x 64 codes; frags 16x16x32; A (x) frags persistent in VGPR.
__global__ __launch_bounds__(256) void vq_gemm(const float* __restrict__ x,
                                               const float* __restrict__ e,
                                               const float* __restrict__ enorm,
                                               const unsigned short* __restrict__ ehT,
                                               const unsigned short* __restrict__ elT,
                                               float* __restrict__ out,
                                               float* __restrict__ sum,
                                               int* __restrict__ rcnt,
                                               int* __restrict__ rlist) {
    __shared__ __align__(16) float xs[DD * XPAD];                 // fp32 x tile, lives to epilogue
    __shared__ __align__(16) unsigned short xbh[64 * EPAD];
    __shared__ __align__(16) unsigned short xbl[64 * EPAD];
    __shared__ __align__(16) unsigned short ebuf[2 * 128 * EPAD]; // hi plane, lo plane
    __shared__ float mv1[64 * 2], mv2[64 * 2];
    __shared__ int mi1[64 * 2];
    __shared__ int ks[64];
    __shared__ float red[4];

    const int tid = threadIdx.x;
    const int n0 = blockIdx.x * 64;
    const int b = n0 >> 12;
    const int hw0 = n0 & 4095;

    {   // stage x fp32 [d][p] coalesced
        const int d = tid >> 2, ph = tid & 3;
        const float* src = x + ((b * DD + d) << 12) + hw0 + ph * 16;
        float* dst = &xs[d * XPAD + ph * 16];
#pragma unroll
        for (int j = 0; j < 4; ++j)
            *(float4*)(dst + j * 4) = *(const float4*)(src + j * 4);
    }
    __syncthreads();
    {   // transpose + split to bf16 [p][d]
        const int p = tid >> 2, dq = tid & 3;
#pragma unroll
        for (int s = 0; s < 16; ++s) {
            const int d = dq * 16 + s;
            const float f = xs[d * XPAD + p];
            const unsigned short h = bf16_rne(f);
            xbh[p * EPAD + d] = h;
            xbl[p * EPAD + d] = bf16_rne(f - bf16_to_f(h));
        }
    }
    __syncthreads();

    const int wave = tid >> 6, lane = tid & 63;
    const int ln15 = lane & 15, q8 = (lane >> 4) * 8;
    const int wp = (wave >> 1) * 32;   // point base of this wave
    const int wc = (wave & 1) * 64;    // code base within codetile

    short8 ah[2][2], al[2][2];         // persistent A frags [rf][kc]
#pragma unroll
    for (int rf = 0; rf < 2; ++rf)
#pragma unroll
        for (int kc = 0; kc < 2; ++kc) {
            const int base = (wp + rf * 16 + ln15) * EPAD + kc * 32 + q8;
            ah[rf][kc] = *(const short8*)(xbh + base);
            al[rf][kc] = *(const short8*)(xbl + base);
        }

    float v1[8], v2[8];
    int i1[8];
#pragma unroll
    for (int r = 0; r < 8; ++r) { v1[r] = 3.4e38f; v2[r] = 3.4e38f; i1[r] = 0; }

    const unsigned short* ebH = ebuf;
    const unsigned short* ebL = ebuf + 128 * EPAD;

    for (int kt = 0; kt < 8; ++kt) {
        __syncthreads();               // previous tile's frag reads done
        {   // stage e tile: raw copy of 2x18432B padded-row slices
            const char* srcH = (const char*)(ehT + kt * 128 * EPAD);
            const char* srcL = (const char*)(elT + kt * 128 * EPAD);
            char* dstc = (char*)ebuf;
#pragma unroll
            for (int i = 0; i < 9; ++i) {
                const int o = i * 4096 + tid * 16;
                const char* s = (o < 18432) ? (srcH + o) : (srcL + (o - 18432));
                *(float4*)(dstc + o) = *(const float4*)s;
            }
        }
        __syncthreads();

        float enc[4];
#pragma unroll
        for (int cf = 0; cf < 4; ++cf)
            enc[cf] = enorm[kt * 128 + wc + cf * 16 + ln15];

        f32x4 acc[2][4];
#pragma unroll
        for (int rf = 0; rf < 2; ++rf)
#pragma unroll
            for (int cf = 0; cf < 4; ++cf)
                acc[rf][cf] = (f32x4){0.f, 0.f, 0.f, 0.f};

#pragma unroll
        for (int kc = 0; kc < 2; ++kc) {
            short8 bh[4], bl[4];
#pragma unroll
            for (int cf = 0; cf < 4; ++cf) {
                const int cb = (wc + cf * 16 + ln15) * EPAD + kc * 32 + q8;
                bh[cf] = *(const short8*)(ebH + cb);
                bl[cf] = *(const short8*)(ebL + cb);
            }
#pragma unroll
            for (int rf = 0; rf < 2; ++rf)
#pragma unroll
                for (int cf = 0; cf < 4; ++cf) {
                    acc[rf][cf] = __builtin_amdgcn_mfma_f32_16x16x32_bf16(al[rf][kc], bh[cf], acc[rf][cf], 0, 0, 0);
                    acc[rf][cf] = __builtin_amdgcn_mfma_f32_16x16x32_bf16(ah[rf][kc], bl[cf], acc[rf][cf], 0, 0, 0);
                    acc[rf][cf] = __builtin_amdgcn_mfma_f32_16x16x32_bf16(ah[rf][kc], bh[cf], acc[rf][cf], 0, 0, 0);
                }
        }

        // dist = en - 2*dot; track best + second-best per (rf,reg) row
#pragma unroll
        for (int cf = 0; cf < 4; ++cf) {
            const int col = kt * 128 + wc + cf * 16 + ln15;
#pragma unroll
            for (int rf = 0; rf < 2; ++rf)
#pragma unroll
                for (int reg = 0; reg < 4; ++reg) {
                    const float m = fmaf(-2.f, acc[rf][cf][reg], enc[cf]);
                    const int r = rf * 4 + reg;
                    v2[r] = fminf(v2[r], fmaxf(v1[r], m));
                    const bool t = (m < v1[r]);   // strict <: cols ascend per lane
                    i1[r] = t ? col : i1[r];
                    v1[r] = t ? m : v1[r];
                }
        }
    }

    // cross-lane merge within the 16 lanes sharing each row-set
#pragma unroll
    for (int r = 0; r < 8; ++r) {
#pragma unroll
        for (int msk = 1; msk < 16; msk <<= 1) {
            const float ov = __shfl_xor(v1[r], msk);
            const int oi = __shfl_xor(i1[r], msk);
            const float ov2 = __shfl_xor(v2[r], msk);
            v2[r] = fminf(fminf(v2[r], ov2), fmaxf(v1[r], ov));
            const bool t = (ov < v1[r]) || (ov == v1[r] && oi < i1[r]);
            v1[r] = t ? ov : v1[r];
            i1[r] = t ? oi : i1[r];
        }
    }
    if (ln15 == 0) {
        const int q = lane >> 4;
        const int h = wave & 1;
#pragma unroll
        for (int r = 0; r < 8; ++r) {
            const int pt = wp + (r >> 2) * 16 + q * 4 + (r & 3);
            mv1[pt * 2 + h] = v1[r];
            mi1[pt * 2 + h] = i1[r];
            mv2[pt * 2 + h] = v2[r];
        }
    }
    __syncthreads();
    if (tid < 64) {   // merge the two code-half waves
        const float va = mv1[tid * 2], vb = mv1[tid * 2 + 1];
        const int ia = mi1[tid * 2], ib = mi1[tid * 2 + 1];
        const bool t = (vb < va) || (vb == va && ib < ia);
        const float bv = t ? vb : va;
        const int bi = t ? ib : ia;
        const float sec = fminf(fminf(mv2[tid * 2], mv2[tid * 2 + 1]), fmaxf(va, vb));
        ks[tid] = bi;
        out[OFF_IDX + n0 + tid] = (float)bi;
        if (sec - bv < MARGIN) {      // ambiguous under bf16x3 error bound
            const int w = atomicAdd(rcnt, 1);
            if (w < RESCUE_CAP) rlist[w] = n0 + tid;
        }
    }
    __syncthreads();

    // quantize + loss epilogue (fp32 x still in LDS)
    const int p = tid & 63, dqr = tid >> 6;
    const int kp = ks[p];
    float lacc = 0.f;
#pragma unroll
    for (int s = 0; s < 16; ++s) {
        const int d = dqr * 16 + s;
        const float qv = e[d * KK + kp];
        const float xv = xs[d * XPAD + p];
        out[((b * DD + d) << 12) + hw0 + p] = qv;
        const float df = xv - qv;
        lacc = fmaf(df, df, lacc);
    }
#pragma unroll
    for (int off = 32; off > 0; off >>= 1) lacc += __shfl_down(lacc, off, 64);
    if (lane == 0) red[wave] = lacc;
    __syncthreads();
    if (tid == 0) atomicAdd(sum, red[0] + red[1] + red[2] + red[3]);
}

// ---------- kernel 3: exact fp32 rescue for ambiguous points ----------
__global__ __launch_bounds__(256) void rescue_kernel(const float* __restrict__ x,
                                                     const float* __restrict__ e,
                                                     const float* __restrict__ enorm,
                                                     const int* __restrict__ rcnt,
                                                     const int* __restrict__ rlist,
                                                     float* __restrict__ out,
                                                     float* __restrict__ sum) {
    __shared__ float xp[64];
    __shared__ float bvs[256];
    __shared__ int bis[256];
    __shared__ int fix[2];
    const int tid = threadIdx.x;
    int cnt = *rcnt;
    if (cnt > RESCUE_CAP) cnt = RESCUE_CAP;
    for (int it = blockIdx.x; it < cnt; it += gridDim.x) {
        const int pn = rlist[it];
        const int b = pn >> 12, hw = pn & 4095;
        if (tid < 64) xp[tid] = x[((b * DD + tid) << 12) + hw];
        __syncthreads();
        float dot[4] = {0.f, 0.f, 0.f, 0.f};
#pragma unroll 8
        for (int d = 0; d < DD; ++d) {
            const float xv = xp[d];
            const float4 ev = *(const float4*)(e + d * KK + tid * 4);
            dot[0] = fmaf(xv, ev.x, dot[0]);
            dot[1] = fmaf(xv, ev.y, dot[1]);
            dot[2] = fmaf(xv, ev.z, dot[2]);
            dot[3] = fmaf(xv, ev.w, dot[3]);
        }
        float bv = 3.4e38f;
        int bi = 0;
#pragma unroll
        for (int c = 0; c < 4; ++c) {
            const float dist = fmaf(-2.f, dot[c], enorm[tid * 4 + c]);
            if (dist < bv) { bv = dist; bi = tid * 4 + c; }
        }
        bvs[tid] = bv;
        bis[tid] = bi;
        __syncthreads();
        if (tid == 0) {
            float gb = bvs[0];
            int gi = bis[0];
            for (int t = 1; t < 256; ++t) {
                const float v = bvs[t];
                if (v < gb || (v == gb && bis[t] < gi)) { gb = v; gi = bis[t]; }
            }
            const int kold = (int)out[OFF_IDX + pn];
            fix[0] = (gi != kold) ? gi : -1;
            fix[1] = kold;
        }
        __syncthreads();
        const int kn = fix[0];
        if (kn >= 0 && tid < 64) {
            const int d = tid;
            const float qn = e[d * KK + kn];
            const float qo = e[d * KK + fix[1]];
            const float xv = xp[d];
            out[((b * DD + d) << 12) + hw] = qn;
            float delta = (xv - qn) * (xv - qn) - (xv - qo) * (xv - qo);
#pragma unroll
            for (int off = 32; off > 0; off >>= 1) delta += __shfl_down(delta, off, 64);
            if (tid == 0) {
                atomicAdd(sum, delta);
                out[OFF_IDX + pn] = (float)kn;
            }
        }
        __syncthreads();
    }
}

// ---------- kernel 4: finalize losses (after rescue adjustments) ----------
__global__ void finalize_kernel(const float* __restrict__ sum, float* __restrict__ out) {
    const float m = sum[0] * (1.0f / (float)TOTAL);
    out[OFF_L1] = m;   // dictionary_loss
    out[OFF_L2] = m;   // commitment_loss (numerically identical)
}

extern "C" void kernel_launch(void* const* d_in, const int* in_sizes, int n_in,
                              void* d_out, int out_size, void* d_ws, size_t ws_size,
                              hipStream_t stream) {
    const float* x = (const float*)d_in[0];      // [16,64,64,64]
    const float* e = (const float*)d_in[1];      // [64,1024]
    float* out = (float*)d_out;

    float* sum = (float*)d_ws;
    int* rcnt = (int*)d_ws + 1;
    float* enorm = (float*)d_ws + WS_ENORM_F;
    int* rlist = (int*)d_ws + WS_LIST_I;
    unsigned short* ehT = (unsigned short*)((char*)d_ws + WS_EHT_BYTE);
    unsigned short* elT = (unsigned short*)((char*)d_ws + WS_ELT_BYTE);

    hipMemsetAsync(d_ws, 0, 16, stream);         // sum + rescue_cnt
    prep_kernel<<<16, 256, 0, stream>>>(e, enorm, ehT, elT);
    vq_gemm<<<NPTS / 64, 256, 0, stream>>>(x, e, enorm, ehT, elT, out, sum, rcnt, rlist);
    rescue_kernel<<<256, 256, 0, stream>>>(x, e, enorm, rcnt, rlist, out, sum);
    finalize_kernel<<<1, 1, 0, stream>>>(sum, out);
}

// Round 10
// 134.951 us; speedup vs baseline: 4.3869x; 1.4165x over previous
//
#include <hip/hip_runtime.h>

// VectorQuantizer: B=16, D=64, H=64, W=64, K=1024
#define DD 64
#define KK 1024
#define NPTS 65536
#define TOTAL 4194304

// Output layout (flat f32): quantized[4194304], L1, L2, idx[65536]
#define OFF_L1 4194304
#define OFF_L2 4194305
#define OFF_IDX 4194306

// ws layout: [0] f32 sum, [1] i32 rescue_cnt, [2] u32 ticket, enorm @ float 64,
// rescue list @ int 1088 (cap 8192), ehT @ byte 65536, elT after.
#define WS_ENORM_F 64
#define WS_LIST_I 1088
#define RESCUE_CAP 8192
#define WS_EHT_BYTE 65536
#define WS_ELT_BYTE (65536 + 1024 * 72 * 2)

#define EPAD 72       // padded d-stride (ushorts) for bf16 rows [k][d]
#define XPAD 68       // padded stride (floats) for fp32 LDS tiles
#define MARGIN 0.01f  // >=6x worst-case bf16x3+MFMA distance error (~1.5e-3)

#define RGRID 512     // rescue grid (fixed, graph-capture safe)

typedef __attribute__((ext_vector_type(8))) short short8;
typedef __attribute__((ext_vector_type(4))) float f32x4;

__device__ __forceinline__ unsigned short bf16_rne(float f) {
    unsigned b = __float_as_uint(f);
    return (unsigned short)((b + 0x7FFFu + ((b >> 16) & 1u)) >> 16);
}
__device__ __forceinline__ float bf16_to_f(unsigned short h) {
    return __uint_as_float(((unsigned)h) << 16);
}

// ---------- kernel 1: enorm + split-transpose codebook to [k][d] bf16 hi/lo ----------
__global__ __launch_bounds__(256) void prep_kernel(const float* __restrict__ e,
                                                   float* __restrict__ enorm,
                                                   unsigned short* __restrict__ ehT,
                                                   unsigned short* __restrict__ elT) {
    __shared__ __align__(16) float et[DD * XPAD];
    __shared__ float enred[64 * 4];
    const int tid = threadIdx.x;
    const int k0 = blockIdx.x * 64;
    {   // load e[d][k0..k0+63] coalesced
        const int d = tid >> 2, kq = tid & 3;
#pragma unroll
        for (int j = 0; j < 4; ++j) {
            const int kk = kq * 16 + j * 4;
            *(float4*)(&et[d * XPAD + kk]) = *(const float4*)(e + d * KK + k0 + kk);
        }
    }
    __syncthreads();
    const int k = tid >> 2, dq = tid & 3;
    unsigned hu[8], lu[8];
    float s2 = 0.f;
#pragma unroll
    for (int s = 0; s < 16; s += 2) {
        const int d0 = dq * 16 + s;
        const float f0 = et[d0 * XPAD + k];
        const float f1 = et[(d0 + 1) * XPAD + k];
        s2 = fmaf(f0, f0, s2);
        s2 = fmaf(f1, f1, s2);
        const unsigned short h0 = bf16_rne(f0), h1 = bf16_rne(f1);
        const unsigned short l0 = bf16_rne(f0 - bf16_to_f(h0));
        const unsigned short l1 = bf16_rne(f1 - bf16_to_f(h1));
        hu[s >> 1] = (unsigned)h0 | ((unsigned)h1 << 16);
        lu[s >> 1] = (unsigned)l0 | ((unsigned)l1 << 16);
    }
    const int row = (k0 + k) * EPAD + dq * 16;
    *(uint4*)(ehT + row) = make_uint4(hu[0], hu[1], hu[2], hu[3]);
    *(uint4*)(ehT + row + 8) = make_uint4(hu[4], hu[5], hu[6], hu[7]);
    *(uint4*)(elT + row) = make_uint4(lu[0], lu[1], lu[2], lu[3]);
    *(uint4*)(elT + row + 8) = make_uint4(lu[4], lu[5], lu[6], lu[7]);
    enred[k * 4 + dq] = s2;
    __syncthreads();
    if (tid < 64)
        enorm[k0 + tid] = enred[tid * 4] + enred[tid * 4 + 1] + enred[tid * 4 + 2] + enred[tid * 4 + 3];
}

// ---------- kernel 2: MFMA bf16x3 distances + argmin(+2nd best) + quantize + loss ----------
__global__ __launch_bounds__(256) void vq_gemm(const float* __restrict__ x,
                                               const float* __restrict__ e,
                                               const float* __restrict__ enorm,
                                               const unsigned short* __restrict__ ehT,
                                               const unsigned short* __restrict__ elT,
                                               float* __restrict__ out,
                                               float* __restrict__ sum,
                                               int* __restrict__ rcnt,
                                               int* __restrict__ rlist) {
    __shared__ __align__(16) float xs[DD * XPAD];                 // fp32 x tile, lives to epilogue
    __shared__ __align__(16) unsigned short xbh[64 * EPAD];
    __shared__ __align__(16) unsigned short xbl[64 * EPAD];
    __shared__ __align__(16) unsigned short ebuf[2 * 128 * EPAD]; // hi plane, lo plane
    __shared__ float mv1[64 * 2], mv2[64 * 2];
    __shared__ int mi1[64 * 2];
    __shared__ int ks[64];
    __shared__ float red[4];

    const int tid = threadIdx.x;
    const int n0 = blockIdx.x * 64;
    const int b = n0 >> 12;
    const int hw0 = n0 & 4095;

    {   // stage x fp32 [d][p] coalesced
        const int d = tid >> 2, ph = tid & 3;
        const float* src = x + ((b * DD + d) << 12) + hw0 + ph * 16;
        float* dst = &xs[d * XPAD + ph * 16];
#pragma unroll
        for (int j = 0; j < 4; ++j)
            *(float4*)(dst + j * 4) = *(const float4*)(src + j * 4);
    }
    __syncthreads();
    {   // transpose + split to bf16 [p][d]
        const int p = tid >> 2, dq = tid & 3;
#pragma unroll
        for (int s = 0; s < 16; ++s) {
            const int d = dq * 16 + s;
            const float f = xs[d * XPAD + p];
            const unsigned short h = bf16_rne(f);
            xbh[p * EPAD + d] = h;
            xbl[p * EPAD + d] = bf16_rne(f - bf16_to_f(h));
        }
    }
    __syncthreads();

    const int wave = tid >> 6, lane = tid & 63;
    const int ln15 = lane & 15, q8 = (lane >> 4) * 8;
    const int wp = (wave >> 1) * 32;   // point base of this wave
    const int wc = (wave & 1) * 64;    // code base within codetile

    short8 ah[2][2], al[2][2];         // persistent A frags [rf][kc]
#pragma unroll
    for (int rf = 0; rf < 2; ++rf)
#pragma unroll
        for (int kc = 0; kc < 2; ++kc) {
            const int base = (wp + rf * 16 + ln15) * EPAD + kc * 32 + q8;
            ah[rf][kc] = *(const short8*)(xbh + base);
            al[rf][kc] = *(const short8*)(xbl + base);
        }

    float v1[8], v2[8];
    int i1[8];
#pragma unroll
    for (int r = 0; r < 8; ++r) { v1[r] = 3.4e38f; v2[r] = 3.4e38f; i1[r] = 0; }

    const unsigned short* ebH = ebuf;
    const unsigned short* ebL = ebuf + 128 * EPAD;

    for (int kt = 0; kt < 8; ++kt) {
        __syncthreads();               // previous tile's frag reads done
        {   // stage e tile: raw copy of 2x18432B padded-row slices
            const char* srcH = (const char*)(ehT + kt * 128 * EPAD);
            const char* srcL = (const char*)(elT + kt * 128 * EPAD);
            char* dstc = (char*)ebuf;
#pragma unroll
            for (int i = 0; i < 9; ++i) {
                const int o = i * 4096 + tid * 16;
                const char* s = (o < 18432) ? (srcH + o) : (srcL + (o - 18432));
                *(float4*)(dstc + o) = *(const float4*)s;
            }
        }
        __syncthreads();

        float enc[4];
#pragma unroll
        for (int cf = 0; cf < 4; ++cf)
            enc[cf] = enorm[kt * 128 + wc + cf * 16 + ln15];

        f32x4 acc[2][4];
#pragma unroll
        for (int rf = 0; rf < 2; ++rf)
#pragma unroll
            for (int cf = 0; cf < 4; ++cf)
                acc[rf][cf] = (f32x4){0.f, 0.f, 0.f, 0.f};

#pragma unroll
        for (int kc = 0; kc < 2; ++kc) {
            short8 bh[4], bl[4];
#pragma unroll
            for (int cf = 0; cf < 4; ++cf) {
                const int cb = (wc + cf * 16 + ln15) * EPAD + kc * 32 + q8;
                bh[cf] = *(const short8*)(ebH + cb);
                bl[cf] = *(const short8*)(ebL + cb);
            }
#pragma unroll
            for (int rf = 0; rf < 2; ++rf)
#pragma unroll
                for (int cf = 0; cf < 4; ++cf) {
                    acc[rf][cf] = __builtin_amdgcn_mfma_f32_16x16x32_bf16(al[rf][kc], bh[cf], acc[rf][cf], 0, 0, 0);
                    acc[rf][cf] = __builtin_amdgcn_mfma_f32_16x16x32_bf16(ah[rf][kc], bl[cf], acc[rf][cf], 0, 0, 0);
                    acc[rf][cf] = __builtin_amdgcn_mfma_f32_16x16x32_bf16(ah[rf][kc], bh[cf], acc[rf][cf], 0, 0, 0);
                }
        }

        // dist = en - 2*dot; track best + second-best per (rf,reg) row
#pragma unroll
        for (int cf = 0; cf < 4; ++cf) {
            const int col = kt * 128 + wc + cf * 16 + ln15;
#pragma unroll
            for (int rf = 0; rf < 2; ++rf)
#pragma unroll
                for (int reg = 0; reg < 4; ++reg) {
                    const float m = fmaf(-2.f, acc[rf][cf][reg], enc[cf]);
                    const int r = rf * 4 + reg;
                    v2[r] = fminf(v2[r], fmaxf(v1[r], m));
                    const bool t = (m < v1[r]);   // strict <: cols ascend per lane
                    i1[r] = t ? col : i1[r];
                    v1[r] = t ? m : v1[r];
                }
        }
    }

    // cross-lane merge within the 16 lanes sharing each row-set
#pragma unroll
    for (int r = 0; r < 8; ++r) {
#pragma unroll
        for (int msk = 1; msk < 16; msk <<= 1) {
            const float ov = __shfl_xor(v1[r], msk);
            const int oi = __shfl_xor(i1[r], msk);
            const float ov2 = __shfl_xor(v2[r], msk);
            v2[r] = fminf(fminf(v2[r], ov2), fmaxf(v1[r], ov));
            const bool t = (ov < v1[r]) || (ov == v1[r] && oi < i1[r]);
            v1[r] = t ? ov : v1[r];
            i1[r] = t ? oi : i1[r];
        }
    }
    if (ln15 == 0) {
        const int q = lane >> 4;
        const int h = wave & 1;
#pragma unroll
        for (int r = 0; r < 8; ++r) {
            const int pt = wp + (r >> 2) * 16 + q * 4 + (r & 3);
            mv1[pt * 2 + h] = v1[r];
            mi1[pt * 2 + h] = i1[r];
            mv2[pt * 2 + h] = v2[r];
        }
    }
    __syncthreads();
    if (tid < 64) {   // merge the two code-half waves
        const float va = mv1[tid * 2], vb = mv1[tid * 2 + 1];
        const int ia = mi1[tid * 2], ib = mi1[tid * 2 + 1];
        const bool t = (vb < va) || (vb == va && ib < ia);
        const float bv = t ? vb : va;
        const int bi = t ? ib : ia;
        const float sec = fminf(fminf(mv2[tid * 2], mv2[tid * 2 + 1]), fmaxf(va, vb));
        ks[tid] = bi;
        out[OFF_IDX + n0 + tid] = (float)bi;
        if (sec - bv < MARGIN) {      // ambiguous under bf16x3 error bound
            const int w = atomicAdd(rcnt, 1);
            if (w < RESCUE_CAP) rlist[w] = n0 + tid;
        }
    }
    __syncthreads();

    // quantize + loss epilogue (fp32 x still in LDS)
    const int p = tid & 63, dqr = tid >> 6;
    const int kp = ks[p];
    float lacc = 0.f;
#pragma unroll
    for (int s = 0; s < 16; ++s) {
        const int d = dqr * 16 + s;
        const float qv = e[d * KK + kp];
        const float xv = xs[d * XPAD + p];
        out[((b * DD + d) << 12) + hw0 + p] = qv;
        const float df = xv - qv;
        lacc = fmaf(df, df, lacc);
    }
#pragma unroll
    for (int off = 32; off > 0; off >>= 1) lacc += __shfl_down(lacc, off, 64);
    if (lane == 0) red[wave] = lacc;
    __syncthreads();
    if (tid == 0) atomicAdd(sum, red[0] + red[1] + red[2] + red[3]);
}

// ---------- kernel 3: exact fp32 rescue (parallel reduce) + ticketed finalize ----------
__global__ __launch_bounds__(256) void rescue_kernel(const float* __restrict__ x,
                                                     const float* __restrict__ e,
                                                     const float* __restrict__ enorm,
                                                     const int* __restrict__ rcnt,
                                                     const int* __restrict__ rlist,
                                                     float* __restrict__ out,
                                                     float* __restrict__ sum,
                                                     unsigned* __restrict__ tick) {
    __shared__ float xp[64];
    __shared__ float rv[4];
    __shared__ int ri[4];
    __shared__ int fix[2];
    const int tid = threadIdx.x;
    const int lane = tid & 63, wave = tid >> 6;
    int cnt = *rcnt;
    if (cnt > RESCUE_CAP) cnt = RESCUE_CAP;

    for (int it = blockIdx.x; it < cnt; it += gridDim.x) {
        const int pn = rlist[it];
        const int b = pn >> 12, hw = pn & 4095;
        __syncthreads();               // xp reuse across iterations
        if (tid < 64) xp[tid] = x[((b * DD + tid) << 12) + hw];
        __syncthreads();
        float dot[4] = {0.f, 0.f, 0.f, 0.f};
#pragma unroll 8
        for (int d = 0; d < DD; ++d) {
            const float xv = xp[d];
            const float4 ev = *(const float4*)(e + d * KK + tid * 4);
            dot[0] = fmaf(xv, ev.x, dot[0]);
            dot[1] = fmaf(xv, ev.y, dot[1]);
            dot[2] = fmaf(xv, ev.z, dot[2]);
            dot[3] = fmaf(xv, ev.w, dot[3]);
        }
        float bv = 3.4e38f;
        int bi = 0;
#pragma unroll
        for (int c = 0; c < 4; ++c) {
            const float dist = fmaf(-2.f, dot[c], enorm[tid * 4 + c]);
            if (dist < bv) { bv = dist; bi = tid * 4 + c; }   // c ascends -> min idx
        }
        // wave butterfly argmin (tie -> smaller index)
#pragma unroll
        for (int m = 1; m < 64; m <<= 1) {
            const float ov = __shfl_xor(bv, m);
            const int oi = __shfl_xor(bi, m);
            if (ov < bv || (ov == bv && oi < bi)) { bv = ov; bi = oi; }
        }
        if (lane == 0) { rv[wave] = bv; ri[wave] = bi; }
        __syncthreads();
        if (tid == 0) {
            float gb = rv[0];
            int gi = ri[0];
#pragma unroll
            for (int t = 1; t < 4; ++t)
                if (rv[t] < gb || (rv[t] == gb && ri[t] < gi)) { gb = rv[t]; gi = ri[t]; }
            const int kold = (int)out[OFF_IDX + pn];
            fix[0] = (gi != kold) ? gi : -1;
            fix[1] = kold;
        }
        __syncthreads();
        const int kn = fix[0];
        if (kn >= 0 && tid < 64) {
            const int d = tid;
            const float qn = e[d * KK + kn];
            const float qo = e[d * KK + fix[1]];
            const float xv = xp[d];
            out[((b * DD + d) << 12) + hw] = qn;
            float delta = (xv - qn) * (xv - qn) - (xv - qo) * (xv - qo);
#pragma unroll
            for (int off = 32; off > 0; off >>= 1) delta += __shfl_down(delta, off, 64);
            if (tid == 0) {
                atomicAdd(sum, delta);
                out[OFF_IDX + pn] = (float)kn;
            }
        }
    }

    // ticketed finalize: last of the RGRID blocks writes losses
    if (tid == 0) {
        __threadfence();
        const unsigned old = atomicAdd(tick, 1u);
        if (old == (unsigned)(gridDim.x - 1)) {
            const float s = atomicAdd(sum, 0.0f);
            const float m = s * (1.0f / (float)TOTAL);
            out[OFF_L1] = m;   // dictionary_loss
            out[OFF_L2] = m;   // commitment_loss (numerically identical)
        }
    }
}

extern "C" void kernel_launch(void* const* d_in, const int* in_sizes, int n_in,
                              void* d_out, int out_size, void* d_ws, size_t ws_size,
                              hipStream_t stream) {
    const float* x = (const float*)d_in[0];      // [16,64,64,64]
    const float* e = (const float*)d_in[1];      // [64,1024]
    float* out = (float*)d_out;

    float* sum = (float*)d_ws;
    int* rcnt = (int*)d_ws + 1;
    unsigned* tick = (unsigned*)d_ws + 2;
    float* enorm = (float*)d_ws + WS_ENORM_F;
    int* rlist = (int*)d_ws + WS_LIST_I;
    unsigned short* ehT = (unsigned short*)((char*)d_ws + WS_EHT_BYTE);
    unsigned short* elT = (unsigned short*)((char*)d_ws + WS_ELT_BYTE);

    hipMemsetAsync(d_ws, 0, 16, stream);         // sum + rescue_cnt + ticket
    prep_kernel<<<16, 256, 0, stream>>>(e, enorm, ehT, elT);
    vq_gemm<<<NPTS / 64, 256, 0, stream>>>(x, e, enorm, ehT, elT, out, sum, rcnt, rlist);
    rescue_kernel<<<RGRID, 256, 0, stream>>>(x, e, enorm, rcnt, rlist, out, sum, tick);
}

// Round 12
// 134.530 us; speedup vs baseline: 4.4006x; 1.0031x over previous
//
#include <hip/hip_runtime.h>

// VectorQuantizer: B=16, D=64, H=64, W=64, K=1024
#define DD 64
#define KK 1024
#define NPTS 65536
#define TOTAL 4194304

// Output layout (flat f32): quantized[4194304], L1, L2, idx[65536]
#define OFF_L1 4194304
#define OFF_L2 4194305
#define OFF_IDX 4194306

// ws layout: [0] f32 sum, [1] i32 rescue_cnt, [2] u32 ticket, enorm @ float 64,
// rescue list @ int 1088 (cap 8192), ehT @ byte 65536, elT after.
#define WS_ENORM_F 64
#define WS_LIST_I 1088
#define RESCUE_CAP 8192
#define WS_EHT_BYTE 65536
#define WS_ELT_BYTE (65536 + 1024 * 72 * 2)

#define EPAD 72       // padded d-stride (ushorts) for bf16 rows [k][d]
#define XPAD 68       // padded stride (floats) for fp32 LDS tiles
#define MARGIN 0.01f  // >=6x worst-case bf16x3+MFMA distance error (~1.5e-3)

#define RGRID 512     // rescue grid (fixed, graph-capture safe)

typedef __attribute__((ext_vector_type(8))) short short8;
typedef __attribute__((ext_vector_type(4))) float f32x4;

__device__ __forceinline__ unsigned short bf16_rne(float f) {
    unsigned b = __float_as_uint(f);
    return (unsigned short)((b + 0x7FFFu + ((b >> 16) & 1u)) >> 16);
}
__device__ __forceinline__ float bf16_to_f(unsigned short h) {
    return __uint_as_float(((unsigned)h) << 16);
}

// ---------- kernel 1: enorm + split codebook to [k][d] bf16 hi/lo ----------
// Grid 256, one wave per code (lane = d). Gather read (stride 4KB) is
// L2-absorbed across 1024 waves; stores 128B-contiguous per wave.
// Block 0 also zeroes the scalar accumulators (replaces hipMemsetAsync).
__global__ __launch_bounds__(256) void prep_kernel(const float* __restrict__ e,
                                                   float* __restrict__ enorm,
                                                   unsigned short* __restrict__ ehT,
                                                   unsigned short* __restrict__ elT,
                                                   float* __restrict__ sum,
                                                   int* __restrict__ rcnt,
                                                   unsigned* __restrict__ tick) {
    const int tid = threadIdx.x;
    if (blockIdx.x == 0 && tid == 0) { *sum = 0.f; *rcnt = 0; *tick = 0u; }
    const int wave = tid >> 6, lane = tid & 63;
    const int k = blockIdx.x * 4 + wave;      // this wave's code
    const float v = e[lane * KK + k];         // lane = d
    const unsigned short h = bf16_rne(v);
    const unsigned short l = bf16_rne(v - bf16_to_f(h));
    ehT[k * EPAD + lane] = h;
    elT[k * EPAD + lane] = l;
    float s2 = v * v;
#pragma unroll
    for (int m = 32; m > 0; m >>= 1) s2 += __shfl_down(s2, m, 64);
    if (lane == 0) enorm[k] = s2;
}

// ---------- kernel 2: MFMA bf16x3 distances + argmin(+2nd best) + quantize + loss ----------
__global__ __launch_bounds__(256) void vq_gemm(const float* __restrict__ x,
                                               const float* __restrict__ e,
                                               const float* __restrict__ enorm,
                                               const unsigned short* __restrict__ ehT,
                                               const unsigned short* __restrict__ elT,
                                               float* __restrict__ out,
                                               float* __restrict__ sum,
                                               int* __restrict__ rcnt,
                                               int* __restrict__ rlist) {
    __shared__ __align__(16) float xs[DD * XPAD];                 // fp32 x tile, lives to epilogue
    __shared__ __align__(16) unsigned short xbh[64 * EPAD];
    __shared__ __align__(16) unsigned short xbl[64 * EPAD];
    __shared__ __align__(16) unsigned short ebuf[2 * 128 * EPAD]; // hi plane, lo plane
    __shared__ float mv1[64 * 2], mv2[64 * 2];
    __shared__ int mi1[64 * 2];
    __shared__ int ks[64];
    __shared__ float red[4];

    const int tid = threadIdx.x;
    const int n0 = blockIdx.x * 64;
    const int b = n0 >> 12;
    const int hw0 = n0 & 4095;

    {   // stage x fp32 [d][p] coalesced
        const int d = tid >> 2, ph = tid & 3;
        const float* src = x + ((b * DD + d) << 12) + hw0 + ph * 16;
        float* dst = &xs[d * XPAD + ph * 16];
#pragma unroll
        for (int j = 0; j < 4; ++j)
            *(float4*)(dst + j * 4) = *(const float4*)(src + j * 4);
    }
    __syncthreads();
    {   // transpose + split to bf16 [p][d]
        const int p = tid >> 2, dq = tid & 3;
#pragma unroll
        for (int s = 0; s < 16; ++s) {
            const int d = dq * 16 + s;
            const float f = xs[d * XPAD + p];
            const unsigned short h = bf16_rne(f);
            xbh[p * EPAD + d] = h;
            xbl[p * EPAD + d] = bf16_rne(f - bf16_to_f(h));
        }
    }
    __syncthreads();

    const int wave = tid >> 6, lane = tid & 63;
    const int ln15 = lane & 15, q8 = (lane >> 4) * 8;
    const int wp = (wave >> 1) * 32;   // point base of this wave
    const int wc = (wave & 1) * 64;    // code base within codetile

    short8 ah[2][2], al[2][2];         // persistent A frags [rf][kc]
#pragma unroll
    for (int rf = 0; rf < 2; ++rf)
#pragma unroll
        for (int kc = 0; kc < 2; ++kc) {
            const int base = (wp + rf * 16 + ln15) * EPAD + kc * 32 + q8;
            ah[rf][kc] = *(const short8*)(xbh + base);
            al[rf][kc] = *(const short8*)(xbl + base);
        }

    float v1[8], v2[8];
    int i1[8];
#pragma unroll
    for (int r = 0; r < 8; ++r) { v1[r] = 3.4e38f; v2[r] = 3.4e38f; i1[r] = 0; }

    const unsigned short* ebH = ebuf;
    const unsigned short* ebL = ebuf + 128 * EPAD;

    for (int kt = 0; kt < 8; ++kt) {
        __syncthreads();               // previous tile's frag reads done
        {   // stage e tile: raw copy of 2x18432B padded-row slices
            const char* srcH = (const char*)(ehT + kt * 128 * EPAD);
            const char* srcL = (const char*)(elT + kt * 128 * EPAD);
            char* dstc = (char*)ebuf;
#pragma unroll
            for (int i = 0; i < 9; ++i) {
                const int o = i * 4096 + tid * 16;
                const char* s = (o < 18432) ? (srcH + o) : (srcL + (o - 18432));
                *(float4*)(dstc + o) = *(const float4*)s;
            }
        }
        __syncthreads();

        float enc[4];
#pragma unroll
        for (int cf = 0; cf < 4; ++cf)
            enc[cf] = enorm[kt * 128 + wc + cf * 16 + ln15];

        f32x4 acc[2][4];
#pragma unroll
        for (int rf = 0; rf < 2; ++rf)
#pragma unroll
            for (int cf = 0; cf < 4; ++cf)
                acc[rf][cf] = (f32x4){0.f, 0.f, 0.f, 0.f};

#pragma unroll
        for (int kc = 0; kc < 2; ++kc) {
            short8 bh[4], bl[4];
#pragma unroll
            for (int cf = 0; cf < 4; ++cf) {
                const int cb = (wc + cf * 16 + ln15) * EPAD + kc * 32 + q8;
                bh[cf] = *(const short8*)(ebH + cb);
                bl[cf] = *(const short8*)(ebL + cb);
            }
#pragma unroll
            for (int rf = 0; rf < 2; ++rf)
#pragma unroll
                for (int cf = 0; cf < 4; ++cf) {
                    acc[rf][cf] = __builtin_amdgcn_mfma_f32_16x16x32_bf16(al[rf][kc], bh[cf], acc[rf][cf], 0, 0, 0);
                    acc[rf][cf] = __builtin_amdgcn_mfma_f32_16x16x32_bf16(ah[rf][kc], bl[cf], acc[rf][cf], 0, 0, 0);
                    acc[rf][cf] = __builtin_amdgcn_mfma_f32_16x16x32_bf16(ah[rf][kc], bh[cf], acc[rf][cf], 0, 0, 0);
                }
        }

        // dist = en - 2*dot; track best + second-best per (rf,reg) row
#pragma unroll
        for (int cf = 0; cf < 4; ++cf) {
            const int col = kt * 128 + wc + cf * 16 + ln15;
#pragma unroll
            for (int rf = 0; rf < 2; ++rf)
#pragma unroll
                for (int reg = 0; reg < 4; ++reg) {
                    const float m = fmaf(-2.f, acc[rf][cf][reg], enc[cf]);
                    const int r = rf * 4 + reg;
                    v2[r] = fminf(v2[r], fmaxf(v1[r], m));
                    const bool t = (m < v1[r]);   // strict <: cols ascend per lane
                    i1[r] = t ? col : i1[r];
                    v1[r] = t ? m : v1[r];
                }
        }
    }

    // cross-lane merge within the 16 lanes sharing each row-set
#pragma unroll
    for (int r = 0; r < 8; ++r) {
#pragma unroll
        for (int msk = 1; msk < 16; msk <<= 1) {
            const float ov = __shfl_xor(v1[r], msk);
            const int oi = __shfl_xor(i1[r], msk);
            const float ov2 = __shfl_xor(v2[r], msk);
            v2[r] = fminf(fminf(v2[r], ov2), fmaxf(v1[r], ov));
            const bool t = (ov < v1[r]) || (ov == v1[r] && oi < i1[r]);
            v1[r] = t ? ov : v1[r];
            i1[r] = t ? oi : i1[r];
        }
    }
    if (ln15 == 0) {
        const int q = lane >> 4;
        const int h = wave & 1;
#pragma unroll
        for (int r = 0; r < 8; ++r) {
            const int pt = wp + (r >> 2) * 16 + q * 4 + (r & 3);
            mv1[pt * 2 + h] = v1[r];
            mi1[pt * 2 + h] = i1[r];
            mv2[pt * 2 + h] = v2[r];
        }
    }
    __syncthreads();
    if (tid < 64) {   // merge the two code-half waves
        const float va = mv1[tid * 2], vb = mv1[tid * 2 + 1];
        const int ia = mi1[tid * 2], ib = mi1[tid * 2 + 1];
        const bool t = (vb < va) || (vb == va && ib < ia);
        const float bv = t ? vb : va;
        const int bi = t ? ib : ia;
        const float sec = fminf(fminf(mv2[tid * 2], mv2[tid * 2 + 1]), fmaxf(va, vb));
        ks[tid] = bi;
        out[OFF_IDX + n0 + tid] = (float)bi;
        if (sec - bv < MARGIN) {      // ambiguous under bf16x3 error bound
            const int w = atomicAdd(rcnt, 1);
            if (w < RESCUE_CAP) rlist[w] = n0 + tid;
        }
    }
    __syncthreads();

    // quantize + loss epilogue (fp32 x still in LDS)
    const int p = tid & 63, dqr = tid >> 6;
    const int kp = ks[p];
    float lacc = 0.f;
#pragma unroll
    for (int s = 0; s < 16; ++s) {
        const int d = dqr * 16 + s;
        const float qv = e[d * KK + kp];
        const float xv = xs[d * XPAD + p];
        out[((b * DD + d) << 12) + hw0 + p] = qv;
        const float df = xv - qv;
        lacc = fmaf(df, df, lacc);
    }
#pragma unroll
    for (int off = 32; off > 0; off >>= 1) lacc += __shfl_down(lacc, off, 64);
    if (lane == 0) red[wave] = lacc;
    __syncthreads();
    if (tid == 0) atomicAdd(sum, red[0] + red[1] + red[2] + red[3]);
}

// ---------- kernel 3: exact fp32 rescue (parallel reduce) + ticketed finalize ----------
__global__ __launch_bounds__(256) void rescue_kernel(const float* __restrict__ x,
                                                     const float* __restrict__ e,
                                                     const float* __restrict__ enorm,
                                                     const int* __restrict__ rcnt,
                                                     const int* __restrict__ rlist,
                                                     float* __restrict__ out,
                                                     float* __restrict__ sum,
                                                     unsigned* __restrict__ tick) {
    __shared__ float xp[64];
    __shared__ float rv[4];
    __shared__ int ri[4];
    __shared__ int fix[2];
    const int tid = threadIdx.x;
    const int lane = tid & 63, wave = tid >> 6;
    int cnt = *rcnt;
    if (cnt > RESCUE_CAP) cnt = RESCUE_CAP;

    for (int it = blockIdx.x; it < cnt; it += gridDim.x) {
        const int pn = rlist[it];
        const int b = pn >> 12, hw = pn & 4095;
        __syncthreads();               // xp reuse across iterations
        if (tid < 64) xp[tid] = x[((b * DD + tid) << 12) + hw];
        __syncthreads();
        float dot[4] = {0.f, 0.f, 0.f, 0.f};
#pragma unroll 8
        for (int d = 0; d < DD; ++d) {
            const float xv = xp[d];
            const float4 ev = *(const float4*)(e + d * KK + tid * 4);
            dot[0] = fmaf(xv, ev.x, dot[0]);
            dot[1] = fmaf(xv, ev.y, dot[1]);
            dot[2] = fmaf(xv, ev.z, dot[2]);
            dot[3] = fmaf(xv, ev.w, dot[3]);
        }
        float bv = 3.4e38f;
        int bi = 0;
#pragma unroll
        for (int c = 0; c < 4; ++c) {
            const float dist = fmaf(-2.f, dot[c], enorm[tid * 4 + c]);
            if (dist < bv) { bv = dist; bi = tid * 4 + c; }   // c ascends -> min idx
        }
        // wave butterfly argmin (tie -> smaller index)
#pragma unroll
        for (int m = 1; m < 64; m <<= 1) {
            const float ov = __shfl_xor(bv, m);
            const int oi = __shfl_xor(bi, m);
            if (ov < bv || (ov == bv && oi < bi)) { bv = ov; bi = oi; }
        }
        if (lane == 0) { rv[wave] = bv; ri[wave] = bi; }
        __syncthreads();
        if (tid == 0) {
            float gb = rv[0];
            int gi = ri[0];
#pragma unroll
            for (int t = 1; t < 4; ++t)
                if (rv[t] < gb || (rv[t] == gb && ri[t] < gi)) { gb = rv[t]; gi = ri[t]; }
            const int kold = (int)out[OFF_IDX + pn];
            fix[0] = (gi != kold) ? gi : -1;
            fix[1] = kold;
        }
        __syncthreads();
        const int kn = fix[0];
        if (kn >= 0 && tid < 64) {
            const int d = tid;
            const float qn = e[d * KK + kn];
            const float qo = e[d * KK + fix[1]];
            const float xv = xp[d];
            out[((b * DD + d) << 12) + hw] = qn;
            float delta = (xv - qn) * (xv - qn) - (xv - qo) * (xv - qo);
#pragma unroll
            for (int off = 32; off > 0; off >>= 1) delta += __shfl_down(delta, off, 64);
            if (tid == 0) {
                atomicAdd(sum, delta);
                out[OFF_IDX + pn] = (float)kn;
            }
        }
    }

    // ticketed finalize: last of the RGRID blocks writes losses
    if (tid == 0) {
        __threadfence();
        const unsigned old = atomicAdd(tick, 1u);
        if (old == (unsigned)(gridDim.x - 1)) {
            const float s = atomicAdd(sum, 0.0f);
            const float m = s * (1.0f / (float)TOTAL);
            out[OFF_L1] = m;   // dictionary_loss
            out[OFF_L2] = m;   // commitment_loss (numerically identical)
        }
    }
}

extern "C" void kernel_launch(void* const* d_in, const int* in_sizes, int n_in,
                              void* d_out, int out_size, void* d_ws, size_t ws_size,
                              hipStream_t stream) {
    const float* x = (const float*)d_in[0];      // [16,64,64,64]
    const float* e = (const float*)d_in[1];      // [64,1024]
    float* out = (float*)d_out;

    float* sum = (float*)d_ws;
    int* rcnt = (int*)d_ws + 1;
    unsigned* tick = (unsigned*)d_ws + 2;
    float* enorm = (float*)d_ws + WS_ENORM_F;
    int* rlist = (int*)d_ws + WS_LIST_I;
    unsigned short* ehT = (unsigned short*)((char*)d_ws + WS_EHT_BYTE);
    unsigned short* elT = (unsigned short*)((char*)d_ws + WS_ELT_BYTE);

    prep_kernel<<<256, 256, 0, stream>>>(e, enorm, ehT, elT, sum, rcnt, tick);
    vq_gemm<<<NPTS / 64, 256, 0, stream>>>(x, e, enorm, ehT, elT, out, sum, rcnt, rlist);
    rescue_kernel<<<RGRID, 256, 0, stream>>>(x, e, enorm, rcnt, rlist, out, sum, tick);
}

// Round 13
// 132.003 us; speedup vs baseline: 4.4849x; 1.0191x over previous
//
#include <hip/hip_runtime.h>

// VectorQuantizer: B=16, D=64, H=64, W=64, K=1024
#define DD 64
#define KK 1024
#define NPTS 65536
#define TOTAL 4194304

// Output layout (flat f32): quantized[4194304], L1, L2, idx[65536]
#define OFF_L1 4194304
#define OFF_L2 4194305
#define OFF_IDX 4194306

// ws layout: [0] f32 sum, [1] i32 rescue_cnt, [2] u32 ticket, enorm @ float 64,
// rescue list @ int 1088 (cap 8192), ehT @ byte 65536 (128KB), elT @ +131072.
#define WS_ENORM_F 64
#define WS_LIST_I 1088
#define RESCUE_CAP 8192
#define WS_EHT_BYTE 65536
#define WS_ELT_BYTE (65536 + 131072)

#define MARGIN 0.01f  // >=6x worst-case bf16x3+MFMA distance error (~1.5e-3)
#define RGRID 512

typedef __attribute__((ext_vector_type(8))) short short8;
typedef __attribute__((ext_vector_type(4))) float f32x4;

__device__ __forceinline__ unsigned short bf16_rne(float f) {
    unsigned b = __float_as_uint(f);
    return (unsigned short)((b + 0x7FFFu + ((b >> 16) & 1u)) >> 16);
}
__device__ __forceinline__ float bf16_to_f(unsigned short h) {
    return __uint_as_float(((unsigned)h) << 16);
}
// async global->LDS DMA, 16B per lane; LDS dest = wave-uniform base + lane*16
__device__ __forceinline__ void gld_lds16(const void* g, void* l) {
    __builtin_amdgcn_global_load_lds(
        (const __attribute__((address_space(1))) void*)g,
        (__attribute__((address_space(3))) void*)l, 16, 0, 0);
}
// swizzled position of element d within a 64-elem row r (16B-granule XOR key)
__device__ __forceinline__ int swz(int r, int d) {
    return ((d & ~7) ^ ((r & 7) << 3)) | (d & 7);
}

// ---------- kernel 1: enorm + swizzled bf16 hi/lo codebook [k][64] ----------
// Grid 256, one wave per code (lane = d). Zeroes scalar accumulators too.
__global__ __launch_bounds__(256) void prep_kernel(const float* __restrict__ e,
                                                   float* __restrict__ enorm,
                                                   unsigned short* __restrict__ ehT,
                                                   unsigned short* __restrict__ elT,
                                                   float* __restrict__ sum,
                                                   int* __restrict__ rcnt,
                                                   unsigned* __restrict__ tick) {
    const int tid = threadIdx.x;
    if (blockIdx.x == 0 && tid == 0) { *sum = 0.f; *rcnt = 0; *tick = 0u; }
    const int wave = tid >> 6, lane = tid & 63;
    const int k = blockIdx.x * 4 + wave;      // this wave's code
    const float v = e[lane * KK + k];         // lane = d
    const unsigned short h = bf16_rne(v);
    const unsigned short l = bf16_rne(v - bf16_to_f(h));
    const int pos = k * 64 + swz(k, lane);
    ehT[pos] = h;
    elT[pos] = l;
    float s2 = v * v;
#pragma unroll
    for (int m = 32; m > 0; m >>= 1) s2 += __shfl_down(s2, m, 64);
    if (lane == 0) enorm[k] = s2;
}

// ---------- kernel 2: MFMA bf16x3 + async-DMA double-buffered k-loop ----------
// 256 thr = 4 waves; block = 64 pts x 1024 codes (16 tiles of 64 codes).
// Wave tile 32 pts x 32 codes. e-tiles DMA'd global->LDS (16B, swizzled raw),
// double-buffered: one barrier per kt drains tile kt, then tile kt+1 streams
// during compute. LDS ~51KB -> 3 blocks/CU.
__global__ __launch_bounds__(256) void vq_gemm(const float* __restrict__ x,
                                               const float* __restrict__ e,
                                               const float* __restrict__ enorm,
                                               const unsigned short* __restrict__ ehT,
                                               const unsigned short* __restrict__ elT,
                                               float* __restrict__ out,
                                               float* __restrict__ sum,
                                               int* __restrict__ rcnt,
                                               int* __restrict__ rlist) {
    __shared__ __align__(16) char ebuf[2 * 16384];          // [buf][hi 8KB | lo 8KB]
    __shared__ __align__(16) unsigned short xbh[64 * 64];   // swizzled [p][d]
    __shared__ __align__(16) unsigned short xbl[64 * 64];
    __shared__ float mv1[64 * 2], mv2[64 * 2];
    __shared__ int mi1[64 * 2];
    __shared__ int ks[64];
    __shared__ float red[4];

    const int tid = threadIdx.x;
    const int wave = tid >> 6, lane = tid & 63;
    const int n0 = blockIdx.x * 64;
    const int b = n0 >> 12;
    const int hw0 = n0 & 4095;

    const char* ehTb = (const char*)ehT;
    const char* elTb = (const char*)elT;
    const int lofs = wave * 1024 + lane * 16;   // per-lane byte offset in a pass

    // issue tile-0 DMA immediately (lands during x-prep)
    {
        char* db = ebuf;
        gld_lds16(ehTb + lofs,        db + wave * 1024);
        gld_lds16(ehTb + 4096 + lofs, db + 4096 + wave * 1024);
        gld_lds16(elTb + lofs,        db + 8192 + wave * 1024);
        gld_lds16(elTb + 4096 + lofs, db + 12288 + wave * 1024);
    }

    // ---- x prep: stage fp32 [d][p] into buf1 scratch, then split-transpose ----
    float* xsc = (float*)(ebuf + 16384);        // 16KB scratch = buf1
    {
        const int d = tid >> 2, ph = tid & 3;
        const float* src = x + ((b * DD + d) << 12) + hw0 + ph * 16;
        float* dst = xsc + d * 64 + ph * 16;
#pragma unroll
        for (int j = 0; j < 4; ++j)
            *(float4*)(dst + j * 4) = *(const float4*)(src + j * 4);
    }
    __syncthreads();
    {
        const int p = tid >> 2, dq = tid & 3;
#pragma unroll
        for (int s = 0; s < 16; ++s) {
            const int d = dq * 16 + s;
            const float f = xsc[d * 64 + p];
            const unsigned short h = bf16_rne(f);
            const int pos = p * 64 + swz(p, d);
            xbh[pos] = h;
            xbl[pos] = bf16_rne(f - bf16_to_f(h));
        }
    }
    __syncthreads();

    const int ln15 = lane & 15, q8 = (lane >> 4) * 8;
    const int wp = (wave >> 1) * 32;   // point base of this wave
    const int wc = (wave & 1) * 32;    // code base within tile

    short8 ah[2][2], al[2][2];         // persistent A frags [rf][kc]
#pragma unroll
    for (int rf = 0; rf < 2; ++rf)
#pragma unroll
        for (int kc = 0; kc < 2; ++kc) {
            const int pp = wp + rf * 16 + ln15;
            const int pos = pp * 64 + ((kc * 32 + q8) ^ ((pp & 7) << 3));
            ah[rf][kc] = *(const short8*)(xbh + pos);
            al[rf][kc] = *(const short8*)(xbl + pos);
        }

    float v1[8], v2[8];
    int i1[8];
#pragma unroll
    for (int r = 0; r < 8; ++r) { v1[r] = 3.4e38f; v2[r] = 3.4e38f; i1[r] = 0; }

    for (int kt = 0; kt < 16; ++kt) {
        __syncthreads();   // drains tile-kt DMA (vmcnt0) + all waves done with kt-1
        if (kt < 15) {     // stream tile kt+1 into the other buffer
            const int nkt = kt + 1;
            char* db = ebuf + (nkt & 1) * 16384;
            const char* sH = ehTb + nkt * 8192 + lofs;
            const char* sL = elTb + nkt * 8192 + lofs;
            gld_lds16(sH,        db + wave * 1024);
            gld_lds16(sH + 4096, db + 4096 + wave * 1024);
            gld_lds16(sL,        db + 8192 + wave * 1024);
            gld_lds16(sL + 4096, db + 12288 + wave * 1024);
        }
        const unsigned short* ebH = (const unsigned short*)(ebuf + (kt & 1) * 16384);
        const unsigned short* ebL = ebH + 4096;

        float enc[2];
#pragma unroll
        for (int cf = 0; cf < 2; ++cf)
            enc[cf] = enorm[kt * 64 + wc + cf * 16 + ln15];

        f32x4 acc[2][2];
#pragma unroll
        for (int rf = 0; rf < 2; ++rf)
#pragma unroll
            for (int cf = 0; cf < 2; ++cf)
                acc[rf][cf] = (f32x4){0.f, 0.f, 0.f, 0.f};

#pragma unroll
        for (int kc = 0; kc < 2; ++kc) {
            short8 bh[2], bl[2];
#pragma unroll
            for (int cf = 0; cf < 2; ++cf) {
                const int c = wc + cf * 16 + ln15;
                const int pos = c * 64 + ((kc * 32 + q8) ^ ((c & 7) << 3));
                bh[cf] = *(const short8*)(ebH + pos);
                bl[cf] = *(const short8*)(ebL + pos);
            }
#pragma unroll
            for (int rf = 0; rf < 2; ++rf)
#pragma unroll
                for (int cf = 0; cf < 2; ++cf) {
                    acc[rf][cf] = __builtin_amdgcn_mfma_f32_16x16x32_bf16(al[rf][kc], bh[cf], acc[rf][cf], 0, 0, 0);
                    acc[rf][cf] = __builtin_amdgcn_mfma_f32_16x16x32_bf16(ah[rf][kc], bl[cf], acc[rf][cf], 0, 0, 0);
                    acc[rf][cf] = __builtin_amdgcn_mfma_f32_16x16x32_bf16(ah[rf][kc], bh[cf], acc[rf][cf], 0, 0, 0);
                }
        }

        // dist = en - 2*dot; best + second-best per (rf,reg) row
#pragma unroll
        for (int cf = 0; cf < 2; ++cf) {
            const int col = kt * 64 + wc + cf * 16 + ln15;
#pragma unroll
            for (int rf = 0; rf < 2; ++rf)
#pragma unroll
                for (int reg = 0; reg < 4; ++reg) {
                    const float m = fmaf(-2.f, acc[rf][cf][reg], enc[cf]);
                    const int r = rf * 4 + reg;
                    v2[r] = fminf(v2[r], fmaxf(v1[r], m));
                    const bool t = (m < v1[r]);   // strict <: cols ascend per lane
                    i1[r] = t ? col : i1[r];
                    v1[r] = t ? m : v1[r];
                }
        }
    }

    // cross-lane merge within the 16 lanes sharing each row-set
#pragma unroll
    for (int r = 0; r < 8; ++r) {
#pragma unroll
        for (int msk = 1; msk < 16; msk <<= 1) {
            const float ov = __shfl_xor(v1[r], msk);
            const int oi = __shfl_xor(i1[r], msk);
            const float ov2 = __shfl_xor(v2[r], msk);
            v2[r] = fminf(fminf(v2[r], ov2), fmaxf(v1[r], ov));
            const bool t = (ov < v1[r]) || (ov == v1[r] && oi < i1[r]);
            v1[r] = t ? ov : v1[r];
            i1[r] = t ? oi : i1[r];
        }
    }
    if (ln15 == 0) {
        const int q = lane >> 4;
        const int h = wave & 1;
#pragma unroll
        for (int r = 0; r < 8; ++r) {
            const int pt = wp + (r >> 2) * 16 + q * 4 + (r & 3);
            mv1[pt * 2 + h] = v1[r];
            mi1[pt * 2 + h] = i1[r];
            mv2[pt * 2 + h] = v2[r];
        }
    }
    __syncthreads();
    if (tid < 64) {   // merge the two code-half waves
        const float va = mv1[tid * 2], vb = mv1[tid * 2 + 1];
        const int ia = mi1[tid * 2], ib = mi1[tid * 2 + 1];
        const bool t = (vb < va) || (vb == va && ib < ia);
        const float bv = t ? vb : va;
        const int bi = t ? ib : ia;
        const float sec = fminf(fminf(mv2[tid * 2], mv2[tid * 2 + 1]), fmaxf(va, vb));
        ks[tid] = bi;
        out[OFF_IDX + n0 + tid] = (float)bi;
        if (sec - bv < MARGIN) {      // ambiguous under bf16x3 error bound
            const int w = atomicAdd(rcnt, 1);
            if (w < RESCUE_CAP) rlist[w] = n0 + tid;
        }
    }
    __syncthreads();

    // quantize + loss epilogue (exact fp32; x re-read coalesced from global)
    const int p = tid & 63, dqr = tid >> 6;
    const int kp = ks[p];
    float lacc = 0.f;
#pragma unroll
    for (int s = 0; s < 16; ++s) {
        const int d = dqr * 16 + s;
        const float qv = e[d * KK + kp];
        const float xv = x[((b * DD + d) << 12) + hw0 + p];
        out[((b * DD + d) << 12) + hw0 + p] = qv;
        const float df = xv - qv;
        lacc = fmaf(df, df, lacc);
    }
#pragma unroll
    for (int off = 32; off > 0; off >>= 1) lacc += __shfl_down(lacc, off, 64);
    if (lane == 0) red[wave] = lacc;
    __syncthreads();
    if (tid == 0) atomicAdd(sum, red[0] + red[1] + red[2] + red[3]);
}

// ---------- kernel 3: exact fp32 rescue + ticketed finalize ----------
__global__ __launch_bounds__(256) void rescue_kernel(const float* __restrict__ x,
                                                     const float* __restrict__ e,
                                                     const float* __restrict__ enorm,
                                                     const int* __restrict__ rcnt,
                                                     const int* __restrict__ rlist,
                                                     float* __restrict__ out,
                                                     float* __restrict__ sum,
                                                     unsigned* __restrict__ tick) {
    __shared__ float xp[64];
    __shared__ float rv[4];
    __shared__ int ri[4];
    __shared__ int fix[2];
    const int tid = threadIdx.x;
    const int lane = tid & 63, wave = tid >> 6;
    int cnt = *rcnt;
    if (cnt > RESCUE_CAP) cnt = RESCUE_CAP;

    for (int it = blockIdx.x; it < cnt; it += gridDim.x) {
        const int pn = rlist[it];
        const int b = pn >> 12, hw = pn & 4095;
        __syncthreads();
        if (tid < 64) xp[tid] = x[((b * DD + tid) << 12) + hw];
        __syncthreads();
        float dot[4] = {0.f, 0.f, 0.f, 0.f};
#pragma unroll 8
        for (int d = 0; d < DD; ++d) {
            const float xv = xp[d];
            const float4 ev = *(const float4*)(e + d * KK + tid * 4);
            dot[0] = fmaf(xv, ev.x, dot[0]);
            dot[1] = fmaf(xv, ev.y, dot[1]);
            dot[2] = fmaf(xv, ev.z, dot[2]);
            dot[3] = fmaf(xv, ev.w, dot[3]);
        }
        float bv = 3.4e38f;
        int bi = 0;
#pragma unroll
        for (int c = 0; c < 4; ++c) {
            const float dist = fmaf(-2.f, dot[c], enorm[tid * 4 + c]);
            if (dist < bv) { bv = dist; bi = tid * 4 + c; }
        }
#pragma unroll
        for (int m = 1; m < 64; m <<= 1) {
            const float ov = __shfl_xor(bv, m);
            const int oi = __shfl_xor(bi, m);
            if (ov < bv || (ov == bv && oi < bi)) { bv = ov; bi = oi; }
        }
        if (lane == 0) { rv[wave] = bv; ri[wave] = bi; }
        __syncthreads();
        if (tid == 0) {
            float gb = rv[0];
            int gi = ri[0];
#pragma unroll
            for (int t = 1; t < 4; ++t)
                if (rv[t] < gb || (rv[t] == gb && ri[t] < gi)) { gb = rv[t]; gi = ri[t]; }
            const int kold = (int)out[OFF_IDX + pn];
            fix[0] = (gi != kold) ? gi : -1;
            fix[1] = kold;
        }
        __syncthreads();
        const int kn = fix[0];
        if (kn >= 0 && tid < 64) {
            const int d = tid;
            const float qn = e[d * KK + kn];
            const float qo = e[d * KK + fix[1]];
            const float xv = xp[d];
            out[((b * DD + d) << 12) + hw] = qn;
            float delta = (xv - qn) * (xv - qn) - (xv - qo) * (xv - qo);
#pragma unroll
            for (int off = 32; off > 0; off >>= 1) delta += __shfl_down(delta, off, 64);
            if (tid == 0) {
                atomicAdd(sum, delta);
                out[OFF_IDX + pn] = (float)kn;
            }
        }
    }

    if (tid == 0) {
        __threadfence();
        const unsigned old = atomicAdd(tick, 1u);
        if (old == (unsigned)(gridDim.x - 1)) {
            const float s = atomicAdd(sum, 0.0f);
            const float m = s * (1.0f / (float)TOTAL);
            out[OFF_L1] = m;   // dictionary_loss
            out[OFF_L2] = m;   // commitment_loss (numerically identical)
        }
    }
}

extern "C" void kernel_launch(void* const* d_in, const int* in_sizes, int n_in,
                              void* d_out, int out_size, void* d_ws, size_t ws_size,
                              hipStream_t stream) {
    const float* x = (const float*)d_in[0];      // [16,64,64,64]
    const float* e = (const float*)d_in[1];      // [64,1024]
    float* out = (float*)d_out;

    float* sum = (float*)d_ws;
    int* rcnt = (int*)d_ws + 1;
    unsigned* tick = (unsigned*)d_ws + 2;
    float* enorm = (float*)d_ws + WS_ENORM_F;
    int* rlist = (int*)d_ws + WS_LIST_I;
    unsigned short* ehT = (unsigned short*)((char*)d_ws + WS_EHT_BYTE);
    unsigned short* elT = (unsigned short*)((char*)d_ws + WS_ELT_BYTE);

    prep_kernel<<<256, 256, 0, stream>>>(e, enorm, ehT, elT, sum, rcnt, tick);
    vq_gemm<<<NPTS / 64, 256, 0, stream>>>(x, e, enorm, ehT, elT, out, sum, rcnt, rlist);
    rescue_kernel<<<RGRID, 256, 0, stream>>>(x, e, enorm, rcnt, rlist, out, sum, tick);
}

// Round 14
// 130.900 us; speedup vs baseline: 4.5227x; 1.0084x over previous
//
#include <hip/hip_runtime.h>

// VectorQuantizer: B=16, D=64, H=64, W=64, K=1024
#define DD 64
#define KK 1024
#define NPTS 65536
#define TOTAL 4194304

// Output layout (flat f32): quantized[4194304], L1, L2, idx[65536]
#define OFF_L1 4194304
#define OFF_L2 4194305
#define OFF_IDX 4194306

// ws layout: [0] f32 sum, [1] i32 rescue_cnt, [2] u32 ticket, enh @ float 64,
// rescue list @ int 1088 (cap 8192), ehT @ byte 65536 (128KB), elT @ +131072.
#define WS_ENH_F 64
#define WS_LIST_I 1088
#define RESCUE_CAP 8192
#define WS_EHT_BYTE 65536
#define WS_ELT_BYTE (65536 + 131072)

// score = dot(x,e) + 512 - ||e||^2/2  (argmax == argmin distance; +512 keeps
// all scores positive so float bits are monotone -> packed uint compare).
// Rescue margin: 32-ulp granule (<=2e-3) + bf16x3 err (~6e-4) + slack.
#define MARGIN_S 0.006f
#define RGRID 512

typedef __attribute__((ext_vector_type(8))) short short8;
typedef __attribute__((ext_vector_type(4))) float f32x4;

__device__ __forceinline__ unsigned short bf16_rne(float f) {
    unsigned b = __float_as_uint(f);
    return (unsigned short)((b + 0x7FFFu + ((b >> 16) & 1u)) >> 16);
}
__device__ __forceinline__ float bf16_to_f(unsigned short h) {
    return __uint_as_float(((unsigned)h) << 16);
}
__device__ __forceinline__ unsigned umax(unsigned a, unsigned b) { return a > b ? a : b; }
__device__ __forceinline__ unsigned umin(unsigned a, unsigned b) { return a < b ? a : b; }
// async global->LDS DMA, 16B per lane; LDS dest = wave-uniform base + lane*16
__device__ __forceinline__ void gld_lds16(const void* g, void* l) {
    __builtin_amdgcn_global_load_lds(
        (const __attribute__((address_space(1))) void*)g,
        (__attribute__((address_space(3))) void*)l, 16, 0, 0);
}
// swizzled position of element d within a 64-elem row r (16B-granule XOR key)
__device__ __forceinline__ int swz(int r, int d) {
    return ((d & ~7) ^ ((r & 7) << 3)) | (d & 7);
}

// ---------- kernel 1: enh + swizzled bf16 hi/lo codebook [k][64] ----------
__global__ __launch_bounds__(256) void prep_kernel(const float* __restrict__ e,
                                                   float* __restrict__ enh,
                                                   unsigned short* __restrict__ ehT,
                                                   unsigned short* __restrict__ elT,
                                                   float* __restrict__ sum,
                                                   int* __restrict__ rcnt,
                                                   unsigned* __restrict__ tick) {
    const int tid = threadIdx.x;
    if (blockIdx.x == 0 && tid == 0) { *sum = 0.f; *rcnt = 0; *tick = 0u; }
    const int wave = tid >> 6, lane = tid & 63;
    const int k = blockIdx.x * 4 + wave;      // this wave's code
    const float v = e[lane * KK + k];         // lane = d
    const unsigned short h = bf16_rne(v);
    const unsigned short l = bf16_rne(v - bf16_to_f(h));
    const int pos = k * 64 + swz(k, lane);
    ehT[pos] = h;
    elT[pos] = l;
    float s2 = v * v;
#pragma unroll
    for (int m = 32; m > 0; m >>= 1) s2 += __shfl_down(s2, m, 64);
    if (lane == 0) enh[k] = 512.0f - 0.5f * s2;
}

// ---------- kernel 2: MFMA bf16x3 + packed-key argmax + quantize + loss ----------
// 256 thr = 4 waves; block = 64 pts x 1024 codes (16 tiles of 64 codes).
// Wave tile 32 pts x 32 codes. e-tiles DMA'd global->LDS, double-buffered.
// Bookkeeping: key = (bits(score)|31) ^ (kt*2+cf); uint top-2 (4 ops/elem).
__global__ __launch_bounds__(256) void vq_gemm(const float* __restrict__ x,
                                               const float* __restrict__ e,
                                               const float* __restrict__ enh,
                                               const unsigned short* __restrict__ ehT,
                                               const unsigned short* __restrict__ elT,
                                               float* __restrict__ out,
                                               float* __restrict__ sum,
                                               int* __restrict__ rcnt,
                                               int* __restrict__ rlist) {
    __shared__ __align__(16) char ebuf[2 * 16384];          // [buf][hi 8KB | lo 8KB]
    __shared__ __align__(16) unsigned short xbh[64 * 64];   // swizzled [p][d]
    __shared__ __align__(16) unsigned short xbl[64 * 64];
    __shared__ float mv1[64 * 2], mv2[64 * 2];
    __shared__ int mi1[64 * 2];
    __shared__ int ks[64];
    __shared__ float red[4];

    const int tid = threadIdx.x;
    const int wave = tid >> 6, lane = tid & 63;
    const int n0 = blockIdx.x * 64;
    const int b = n0 >> 12;
    const int hw0 = n0 & 4095;

    const char* ehTb = (const char*)ehT;
    const char* elTb = (const char*)elT;
    const int lofs = wave * 1024 + lane * 16;   // per-lane byte offset in a pass

    // issue tile-0 DMA immediately (lands during x-prep)
    {
        char* db = ebuf;
        gld_lds16(ehTb + lofs,        db + wave * 1024);
        gld_lds16(ehTb + 4096 + lofs, db + 4096 + wave * 1024);
        gld_lds16(elTb + lofs,        db + 8192 + wave * 1024);
        gld_lds16(elTb + 4096 + lofs, db + 12288 + wave * 1024);
    }

    // ---- x prep: stage fp32 [d][p] into buf1 scratch, then split-transpose ----
    float* xsc = (float*)(ebuf + 16384);        // 16KB scratch = buf1
    {
        const int d = tid >> 2, ph = tid & 3;
        const float* src = x + ((b * DD + d) << 12) + hw0 + ph * 16;
        float* dst = xsc + d * 64 + ph * 16;
#pragma unroll
        for (int j = 0; j < 4; ++j)
            *(float4*)(dst + j * 4) = *(const float4*)(src + j * 4);
    }
    __syncthreads();
    {
        const int p = tid >> 2, dq = tid & 3;
#pragma unroll
        for (int s = 0; s < 16; ++s) {
            const int d = dq * 16 + s;
            const float f = xsc[d * 64 + p];
            const unsigned short h = bf16_rne(f);
            const int pos = p * 64 + swz(p, d);
            xbh[pos] = h;
            xbl[pos] = bf16_rne(f - bf16_to_f(h));
        }
    }
    __syncthreads();

    const int ln15 = lane & 15, q8 = (lane >> 4) * 8;
    const int wp = (wave >> 1) * 32;   // point base of this wave
    const int wc = (wave & 1) * 32;    // code base within tile

    short8 ah[2][2], al[2][2];         // persistent A frags [rf][kc]
#pragma unroll
    for (int rf = 0; rf < 2; ++rf)
#pragma unroll
        for (int kc = 0; kc < 2; ++kc) {
            const int pp = wp + rf * 16 + ln15;
            const int pos = pp * 64 + ((kc * 32 + q8) ^ ((pp & 7) << 3));
            ah[rf][kc] = *(const short8*)(xbh + pos);
            al[rf][kc] = *(const short8*)(xbl + pos);
        }

    unsigned v1u[8], v2u[8];
#pragma unroll
    for (int r = 0; r < 8; ++r) { v1u[r] = 0u; v2u[r] = 0u; }

    for (int kt = 0; kt < 16; ++kt) {
        __syncthreads();   // drains tile-kt DMA + all waves done with kt-1
        if (kt < 15) {     // stream tile kt+1 into the other buffer
            const int nkt = kt + 1;
            char* db = ebuf + (nkt & 1) * 16384;
            const char* sH = ehTb + nkt * 8192 + lofs;
            const char* sL = elTb + nkt * 8192 + lofs;
            gld_lds16(sH,        db + wave * 1024);
            gld_lds16(sH + 4096, db + 4096 + wave * 1024);
            gld_lds16(sL,        db + 8192 + wave * 1024);
            gld_lds16(sL + 4096, db + 12288 + wave * 1024);
        }
        const unsigned short* ebH = (const unsigned short*)(ebuf + (kt & 1) * 16384);
        const unsigned short* ebL = ebH + 4096;

        // acc init = 512 - ||e||^2/2 (biased argmax score)
        f32x4 acc[2][2];
#pragma unroll
        for (int cf = 0; cf < 2; ++cf) {
            const float ec = enh[kt * 64 + wc + cf * 16 + ln15];
#pragma unroll
            for (int rf = 0; rf < 2; ++rf)
                acc[rf][cf] = (f32x4){ec, ec, ec, ec};
        }

#pragma unroll
        for (int kc = 0; kc < 2; ++kc) {
            short8 bh[2], bl[2];
#pragma unroll
            for (int cf = 0; cf < 2; ++cf) {
                const int c = wc + cf * 16 + ln15;
                const int pos = c * 64 + ((kc * 32 + q8) ^ ((c & 7) << 3));
                bh[cf] = *(const short8*)(ebH + pos);
                bl[cf] = *(const short8*)(ebL + pos);
            }
#pragma unroll
            for (int rf = 0; rf < 2; ++rf)
#pragma unroll
                for (int cf = 0; cf < 2; ++cf) {
                    acc[rf][cf] = __builtin_amdgcn_mfma_f32_16x16x32_bf16(al[rf][kc], bh[cf], acc[rf][cf], 0, 0, 0);
                    acc[rf][cf] = __builtin_amdgcn_mfma_f32_16x16x32_bf16(ah[rf][kc], bl[cf], acc[rf][cf], 0, 0, 0);
                    acc[rf][cf] = __builtin_amdgcn_mfma_f32_16x16x32_bf16(ah[rf][kc], bh[cf], acc[rf][cf], 0, 0, 0);
                }
        }

        // packed-key top-2 per (rf,reg) row: key = (bits|31) ^ col5
        // (low5 = 31^col5 -> umax tie-breaks toward SMALLER col5 = smaller k)
#pragma unroll
        for (int rf = 0; rf < 2; ++rf)
#pragma unroll
            for (int reg = 0; reg < 4; ++reg) {
                const int r = rf * 4 + reg;
                const unsigned k0 = (__float_as_uint(acc[rf][0][reg]) | 31u) ^ (unsigned)(kt * 2 + 0);
                const unsigned k1 = (__float_as_uint(acc[rf][1][reg]) | 31u) ^ (unsigned)(kt * 2 + 1);
                const unsigned a = umax(k0, k1), bb = umin(k0, k1);
                v2u[r] = umax(umax(v2u[r], umin(v1u[r], a)), bb);
                v1u[r] = umax(v1u[r], a);
            }
    }

    // decode + cross-lane merge within the 16 lanes sharing each row-set
#pragma unroll
    for (int r = 0; r < 8; ++r) {
        const unsigned c5 = 31u - (v1u[r] & 31u);
        int col = (int)(c5 >> 1) * 64 + wc + (int)(c5 & 1) * 16 + ln15;
        float val = __uint_as_float(v1u[r] & ~31u);
        float sec = __uint_as_float(v2u[r] & ~31u);
#pragma unroll
        for (int msk = 1; msk < 16; msk <<= 1) {
            const float ov = __shfl_xor(val, msk);
            const int oc = __shfl_xor(col, msk);
            const float os = __shfl_xor(sec, msk);
            sec = fmaxf(fmaxf(sec, os), fminf(val, ov));
            const bool t = (ov > val) || (ov == val && oc < col);
            val = t ? ov : val;
            col = t ? oc : col;
        }
        if (ln15 == 0) {
            const int q = lane >> 4;
            const int h = wave & 1;
            const int pt = wp + (r >> 2) * 16 + q * 4 + (r & 3);
            mv1[pt * 2 + h] = val;
            mi1[pt * 2 + h] = col;
            mv2[pt * 2 + h] = sec;
        }
    }
    __syncthreads();
    if (tid < 64) {   // merge the two code-half waves (argmax, tie -> smaller idx)
        const float va = mv1[tid * 2], vb = mv1[tid * 2 + 1];
        const int ia = mi1[tid * 2], ib = mi1[tid * 2 + 1];
        const bool t = (vb > va) || (vb == va && ib < ia);
        const float bv = t ? vb : va;
        const int bi = t ? ib : ia;
        const float sec = fmaxf(fmaxf(mv2[tid * 2], mv2[tid * 2 + 1]), fminf(va, vb));
        ks[tid] = bi;
        out[OFF_IDX + n0 + tid] = (float)bi;
        if (bv - sec < MARGIN_S) {    // ambiguous under granule+bf16x3 bound
            const int w = atomicAdd(rcnt, 1);
            if (w < RESCUE_CAP) rlist[w] = n0 + tid;
        }
    }
    __syncthreads();

    // quantize + loss epilogue (exact fp32; x re-read coalesced from global)
    const int p = tid & 63, dqr = tid >> 6;
    const int kp = ks[p];
    float lacc = 0.f;
#pragma unroll
    for (int s = 0; s < 16; ++s) {
        const int d = dqr * 16 + s;
        const float qv = e[d * KK + kp];
        const float xv = x[((b * DD + d) << 12) + hw0 + p];
        out[((b * DD + d) << 12) + hw0 + p] = qv;
        const float df = xv - qv;
        lacc = fmaf(df, df, lacc);
    }
#pragma unroll
    for (int off = 32; off > 0; off >>= 1) lacc += __shfl_down(lacc, off, 64);
    if (lane == 0) red[wave] = lacc;
    __syncthreads();
    if (tid == 0) atomicAdd(sum, red[0] + red[1] + red[2] + red[3]);
}

// ---------- kernel 3: exact fp32 rescue (argmax form) + ticketed finalize ----------
__global__ __launch_bounds__(256) void rescue_kernel(const float* __restrict__ x,
                                                     const float* __restrict__ e,
                                                     const float* __restrict__ enh,
                                                     const int* __restrict__ rcnt,
                                                     const int* __restrict__ rlist,
                                                     float* __restrict__ out,
                                                     float* __restrict__ sum,
                                                     unsigned* __restrict__ tick) {
    __shared__ float xp[64];
    __shared__ float rv[4];
    __shared__ int ri[4];
    __shared__ int fix[2];
    const int tid = threadIdx.x;
    const int lane = tid & 63, wave = tid >> 6;
    int cnt = *rcnt;
    if (cnt > RESCUE_CAP) cnt = RESCUE_CAP;

    for (int it = blockIdx.x; it < cnt; it += gridDim.x) {
        const int pn = rlist[it];
        const int b = pn >> 12, hw = pn & 4095;
        __syncthreads();
        if (tid < 64) xp[tid] = x[((b * DD + tid) << 12) + hw];
        __syncthreads();
        float dot[4] = {0.f, 0.f, 0.f, 0.f};
#pragma unroll 8
        for (int d = 0; d < DD; ++d) {
            const float xv = xp[d];
            const float4 ev = *(const float4*)(e + d * KK + tid * 4);
            dot[0] = fmaf(xv, ev.x, dot[0]);
            dot[1] = fmaf(xv, ev.y, dot[1]);
            dot[2] = fmaf(xv, ev.z, dot[2]);
            dot[3] = fmaf(xv, ev.w, dot[3]);
        }
        float bv = -3.4e38f;
        int bi = 0;
#pragma unroll
        for (int c = 0; c < 4; ++c) {
            const float a = dot[c] + enh[tid * 4 + c];     // biased argmax score
            if (a > bv) { bv = a; bi = tid * 4 + c; }      // c ascends -> min idx
        }
#pragma unroll
        for (int m = 1; m < 64; m <<= 1) {
            const float ov = __shfl_xor(bv, m);
            const int oi = __shfl_xor(bi, m);
            if (ov > bv || (ov == bv && oi < bi)) { bv = ov; bi = oi; }
        }
        if (lane == 0) { rv[wave] = bv; ri[wave] = bi; }
        __syncthreads();
        if (tid == 0) {
            float gb = rv[0];
            int gi = ri[0];
#pragma unroll
            for (int t = 1; t < 4; ++t)
                if (rv[t] > gb || (rv[t] == gb && ri[t] < gi)) { gb = rv[t]; gi = ri[t]; }
            const int kold = (int)out[OFF_IDX + pn];
            fix[0] = (gi != kold) ? gi : -1;
            fix[1] = kold;
        }
        __syncthreads();
        const int kn = fix[0];
        if (kn >= 0 && tid < 64) {
            const int d = tid;
            const float qn = e[d * KK + kn];
            const float qo = e[d * KK + fix[1]];
            const float xv = xp[d];
            out[((b * DD + d) << 12) + hw] = qn;
            float delta = (xv - qn) * (xv - qn) - (xv - qo) * (xv - qo);
#pragma unroll
            for (int off = 32; off > 0; off >>= 1) delta += __shfl_down(delta, off, 64);
            if (tid == 0) {
                atomicAdd(sum, delta);
                out[OFF_IDX + pn] = (float)kn;
            }
        }
    }

    if (tid == 0) {
        __threadfence();
        const unsigned old = atomicAdd(tick, 1u);
        if (old == (unsigned)(gridDim.x - 1)) {
            const float s = atomicAdd(sum, 0.0f);
            const float m = s * (1.0f / (float)TOTAL);
            out[OFF_L1] = m;   // dictionary_loss
            out[OFF_L2] = m;   // commitment_loss (numerically identical)
        }
    }
}

extern "C" void kernel_launch(void* const* d_in, const int* in_sizes, int n_in,
                              void* d_out, int out_size, void* d_ws, size_t ws_size,
                              hipStream_t stream) {
    const float* x = (const float*)d_in[0];      // [16,64,64,64]
    const float* e = (const float*)d_in[1];      // [64,1024]
    float* out = (float*)d_out;

    float* sum = (float*)d_ws;
    int* rcnt = (int*)d_ws + 1;
    unsigned* tick = (unsigned*)d_ws + 2;
    float* enh = (float*)d_ws + WS_ENH_F;
    int* rlist = (int*)d_ws + WS_LIST_I;
    unsigned short* ehT = (unsigned short*)((char*)d_ws + WS_EHT_BYTE);
    unsigned short* elT = (unsigned short*)((char*)d_ws + WS_ELT_BYTE);

    prep_kernel<<<256, 256, 0, stream>>>(e, enh, ehT, elT, sum, rcnt, tick);
    vq_gemm<<<NPTS / 64, 256, 0, stream>>>(x, e, enh, ehT, elT, out, sum, rcnt, rlist);
    rescue_kernel<<<RGRID, 256, 0, stream>>>(x, e, enh, rcnt, rlist, out, sum, tick);
}